// Round 7
// baseline (15266.039 us; speedup 1.0000x reference)
//
#include <hip/hip_runtime.h>
#include <hip/hip_bf16.h>

// Leaky-integrator RNN, persistent cooperative kernel, v3.
// B=256, T=2048, N_IN=256, N=512, N_OUT=64, ALPHA=0.1
//
// 16 groups (16 batch rows) x 2 blocks (256 cols) x 8 waves (32 cols).
// W_rec in VGPRs (128 regs, own-K/partner-K split, all constant-indexed).
// x-kernel B-frags in LDS (128 KiB). Own tanh-state half in padded LDS
// (stride 528B). Partner half loaded direct-to-A-fragment via system-scope
// (sc0 sc1, L1/L2-bypass) loads from a fragment-ordered IF buffer; one
// monotonic per-block flag counter, vmcnt(0)-release before atomicAdd.

#define B_SZ  256
#define T_SZ  2048
#define N_IN  256
#define N_H   512
#define N_OUT 64
#define STRIDE 264   // u16 per state row (528 B) — breaks stride-512 conflicts

typedef short bf16x8 __attribute__((ext_vector_type(8)));
typedef float f32x4  __attribute__((ext_vector_type(4)));
typedef unsigned long long u64;

union frag { bf16x8 v; u64 d[2]; unsigned int u[4]; unsigned short s[8]; };

__device__ __forceinline__ unsigned short f2bf(float f) {
    union { float f; unsigned int u; } v; v.f = f;
    v.u += 0x7fffu + ((v.u >> 16) & 1u);   // RNE
    return (unsigned short)(v.u >> 16);
}

__device__ __forceinline__ float fast_tanh(float x) {
    float t = __builtin_amdgcn_exp2f(2.885390081777927f * x);
    return 1.0f - 2.0f * __builtin_amdgcn_rcpf(t + 1.0f);
}

__device__ __forceinline__ unsigned int cvt_pk_bf16(float lo, float hi) {
    unsigned int r;
    asm("v_cvt_pk_bf16_f32 %0, %1, %2" : "=v"(r) : "v"(lo), "v"(hi));
    return r;
}

#define MFMA16(A, B, C) __builtin_amdgcn_mfma_f32_16x16x32_bf16((A), (B), (C), 0, 0, 0)

__global__ __launch_bounds__(512, 1) void rnn_persistent(
    const float* __restrict__ x,        // [B][T][N_IN]
    const float* __restrict__ wk,       // [N_IN][N_H]
    const float* __restrict__ wr,       // [N_H][N_H]
    const float* __restrict__ bias,     // [N_H]
    unsigned short* __restrict__ gbuf,  // [2][16][2][8][4][16][8] bf16 frag-ordered
    unsigned int* __restrict__ flags,   // [16][2] monotonic wave counters
    float* __restrict__ lastb)          // [B][N_H] final f32 state
{
    __shared__ unsigned short ldsK[8 * 16 * 64 * 8];  // 128 KiB: [kc][tile][lane][8]
    __shared__ unsigned short st[2 * 16 * STRIDE];    // 16.5 KiB, 2 parities

    const int tid  = threadIdx.x;
    const int lane = tid & 63;
    const int w    = tid >> 6;            // wave 0..7
    const int bid  = blockIdx.x;           // 0..31
    const int g    = bid & 15;             // group (pair {g, g+16} co-XCD by %8)
    const int h    = bid >> 4;             // col half 0/1
    const int lm   = lane & 15;
    const int lg   = lane >> 4;
    const int row0 = g * 16;
    const int colbase = h * 256;

    for (int i = tid; i < 2 * 16 * STRIDE; i += 512) st[i] = 0;

    // ---- stage x-kernel B-frags into LDS: [kc][tile][lane] 16B, conflict-free
    #pragma unroll
    for (int n = 0; n < 2; ++n) {
        int t = w * 2 + n;
        for (int kc = 0; kc < 8; ++kc) {
            frag f;
            #pragma unroll
            for (int i = 0; i < 8; ++i)
                f.s[i] = f2bf(wk[(size_t)(kc * 32 + lg * 8 + i) * N_H + colbase + t * 16 + lm]);
            *(bf16x8*)&ldsK[((kc * 16 + t) * 64 + lane) * 8] = f.v;
        }
    }

    // ---- W_rec B-frags in VGPRs: own-K chunks and partner-K chunks (const-indexed)
    bf16x8 WFo[2][8], WFp[2][8];
    #pragma unroll
    for (int n = 0; n < 2; ++n) {
        for (int kc = 0; kc < 8; ++kc) {
            frag fo, fp;
            #pragma unroll
            for (int i = 0; i < 8; ++i) {
                int col = colbase + w * 32 + n * 16 + lm;
                fo.s[i] = f2bf(wr[(size_t)((h * 8 + kc) * 32 + lg * 8 + i) * N_H + col]);
                fp.s[i] = f2bf(wr[(size_t)(((1 - h) * 8 + kc) * 32 + lg * 8 + i) * N_H + col]);
            }
            WFo[n][kc] = fo.v;
            WFp[n][kc] = fp.v;
        }
    }

    const float bc0 = 0.1f * bias[colbase + w * 32 + lm];
    const float bc1 = 0.1f * bias[colbase + w * 32 + 16 + lm];

    f32x4 prev0 = {0.f, 0.f, 0.f, 0.f};
    f32x4 prev1 = {0.f, 0.f, 0.f, 0.f};

    unsigned int* myflag = &flags[g * 2 + h];
    unsigned int* pflag  = &flags[g * 2 + (1 - h)];

    const float* xrow = x + (size_t)(row0 + lm) * T_SZ * N_IN + lg * 8;

    __syncthreads();   // ldsK + st zeros visible

    for (int s = 0; s < T_SZ; ++s) {
        const int p = s & 1, q = p ^ 1;

        // ---- A: poll partner flag (one broadcast dword) ----
        if (s > 0) {
            const unsigned int tgt = 8u * (unsigned int)s;
            while (__hip_atomic_load(pflag, __ATOMIC_RELAXED,
                                     __HIP_MEMORY_SCOPE_SYSTEM) < tgt)
                __builtin_amdgcn_s_sleep(1);
        }

        // ---- B: partner A-frag loads, direct to regs (sc1, frag-ordered) ----
        frag P[8];
        {
            const u64* pb = (const u64*)gbuf
                          + ((((size_t)p * 16 + g) * 2 + (1 - h)) * 8) * 128
                          + (lg * 16 + lm) * 2;
            #pragma unroll
            for (int kc = 0; kc < 8; ++kc) {
                P[kc].d[0] = __hip_atomic_load(pb + kc * 128,
                                 __ATOMIC_RELAXED, __HIP_MEMORY_SCOPE_SYSTEM);
                P[kc].d[1] = __hip_atomic_load(pb + kc * 128 + 1,
                                 __ATOMIC_RELAXED, __HIP_MEMORY_SCOPE_SYSTEM);
            }
        }

        // ---- C: own-K T-part from padded LDS ----
        f32x4 a0 = {0.f, 0.f, 0.f, 0.f};
        f32x4 a1 = {0.f, 0.f, 0.f, 0.f};
        const unsigned short* stp = st + p * 16 * STRIDE;
        #pragma unroll
        for (int kc = 0; kc < 8; ++kc) {
            bf16x8 a = *(const bf16x8*)(stp + lm * STRIDE + kc * 32 + lg * 8);
            a0 = MFMA16(a, WFo[0][kc], a0);
            a1 = MFMA16(a, WFo[1][kc], a1);
        }

        // ---- D: x-part (covers partner-load latency) ----
        const float* xp = xrow + (size_t)s * N_IN;
        #pragma unroll
        for (int kc = 0; kc < 8; ++kc) {
            f32x4 xa = *(const f32x4*)(xp + kc * 32);
            f32x4 xb = *(const f32x4*)(xp + kc * 32 + 4);
            frag a;
            a.u[0] = cvt_pk_bf16(xa[0], xa[1]);
            a.u[1] = cvt_pk_bf16(xa[2], xa[3]);
            a.u[2] = cvt_pk_bf16(xb[0], xb[1]);
            a.u[3] = cvt_pk_bf16(xb[2], xb[3]);
            bf16x8 b0 = *(const bf16x8*)&ldsK[((kc * 16 + w * 2) * 64 + lane) * 8];
            bf16x8 b1 = *(const bf16x8*)&ldsK[((kc * 16 + w * 2 + 1) * 64 + lane) * 8];
            a0 = MFMA16(a.v, b0, a0);
            a1 = MFMA16(a.v, b1, a1);
        }

        // ---- E: partner-K T-part (compiler waits vmcnt on P loads) ----
        #pragma unroll
        for (int kc = 0; kc < 8; ++kc) {
            a0 = MFMA16(P[kc].v, WFp[0][kc], a0);
            a1 = MFMA16(P[kc].v, WFp[1][kc], a1);
        }

        // ---- F: epilogue -> own cols of LDS[q] ----
        unsigned short* stq = st + q * 16 * STRIDE;
        #pragma unroll
        for (int n = 0; n < 2; ++n) {
            f32x4 acc = n ? a1 : a0;
            float bc  = n ? bc1 : bc0;
            #pragma unroll
            for (int r = 0; r < 4; ++r) {
                float pv = n ? prev1[r] : prev0[r];
                float ns = 0.9f * pv + 0.1f * acc[r] + bc;
                float o  = fast_tanh(ns);
                if (n) prev1[r] = o; else prev0[r] = o;
                int row = lg * 4 + r;
                stq[row * STRIDE + (w * 2 + n) * 16 + lm] = f2bf(fast_tanh(o));
                if (s == T_SZ - 1)
                    lastb[(size_t)(row0 + row) * N_H + colbase + (w * 2 + n) * 16 + lm] = o;
            }
        }
        if (s == T_SZ - 1) break;

        // ---- G: publish own 1KB slice (frag-ordered), release, count ----
        {
            frag v;
            v.v = *(const bf16x8*)(stq + lm * STRIDE + w * 32 + lg * 8);
            u64* gp = (u64*)gbuf
                    + ((((size_t)q * 16 + g) * 2 + h) * 8 + w) * 128
                    + (lg * 16 + lm) * 2;
            __hip_atomic_store(gp,     v.d[0], __ATOMIC_RELAXED, __HIP_MEMORY_SCOPE_SYSTEM);
            __hip_atomic_store(gp + 1, v.d[1], __ATOMIC_RELAXED, __HIP_MEMORY_SCOPE_SYSTEM);
            asm volatile("s_waitcnt vmcnt(0)" ::: "memory");   // data at IF before flag
            if (lane == 0)
                __hip_atomic_fetch_add(myflag, 1u, __ATOMIC_RELAXED,
                                       __HIP_MEMORY_SCOPE_SYSTEM);
        }

        __syncthreads();   // LDS[q] complete before next step's own-K reads
    }
}

__global__ void dense_kernel(const float* __restrict__ last,
                             const float* __restrict__ dw,   // [N_H][N_OUT]
                             const float* __restrict__ db,   // [N_OUT]
                             float* __restrict__ out)        // [B][N_OUT]
{
    const int b = blockIdx.x;
    const int n = threadIdx.x;
    const float* lr = last + (size_t)b * N_H;
    float acc = db[n];
    #pragma unroll 8
    for (int k = 0; k < N_H; ++k)
        acc += lr[k] * dw[(size_t)k * N_OUT + n];
    out[(size_t)b * N_OUT + n] = acc;
}

extern "C" void kernel_launch(void* const* d_in, const int* in_sizes, int n_in,
                              void* d_out, int out_size, void* d_ws, size_t ws_size,
                              hipStream_t stream) {
    const float* x    = (const float*)d_in[0];
    const float* wk   = (const float*)d_in[1];
    const float* wr   = (const float*)d_in[2];
    const float* bias = (const float*)d_in[3];
    const float* dw   = (const float*)d_in[4];
    const float* db   = (const float*)d_in[5];
    float* out = (float*)d_out;

    const size_t GBUF_BYTES = (size_t)2 * 16 * 2 * 8 * 4 * 16 * 8 * sizeof(unsigned short); // 512 KiB
    const size_t FLAG_BYTES = 16 * 2 * sizeof(unsigned int);

    unsigned short* gbuf  = (unsigned short*)d_ws;
    unsigned int*   flags = (unsigned int*)((char*)d_ws + GBUF_BYTES);
    float*          lastb = (float*)((char*)d_ws + GBUF_BYTES + FLAG_BYTES);

    hipMemsetAsync(d_ws, 0, GBUF_BYTES + FLAG_BYTES, stream);

    void* args[] = { (void*)&x, (void*)&wk, (void*)&wr, (void*)&bias,
                     (void*)&gbuf, (void*)&flags, (void*)&lastb };
    hipLaunchCooperativeKernel(reinterpret_cast<void*>(rnn_persistent),
                               dim3(32), dim3(512), args, 0, stream);

    dense_kernel<<<dim3(B_SZ), dim3(N_OUT), 0, stream>>>(lastb, dw, db, out);
}

// Round 8
// 11356.490 us; speedup vs baseline: 1.3443x; 1.3443x over previous
//
#include <hip/hip_runtime.h>
#include <hip/hip_bf16.h>

// Leaky-integrator RNN, persistent cooperative kernel, v4.
// B=256, T=2048, N_IN=256, N=512, N_OUT=64, ALPHA=0.1
//
// 16 groups (16 batch rows) x 2 blocks (256 cols) x 8 waves (32 cols).
// W_rec in VGPRs/AGPRs (128 regs). Kernel weights pre-converted to a
// block-private global bf16 frag buffer (L2-resident), streamed during the
// H-phase which runs in the publish->flag-arrival shadow. x prefetched 2
// steps ahead via an LDS ring. All cross-block traffic AGENT-scope
// (IF-coherent, no HBM write-through, no cache flushes); per-wave monotonic
// flag adds with vmcnt(0) release ordering.

#define B_SZ  256
#define T_SZ  2048
#define N_IN  256
#define N_H   512
#define N_OUT 64
#define STRIDE 264   // u16 per st row (528 B)   -> 2-way LDS conflicts (free)
#define XPAD  260    // f32 per xbuf row (1040 B) -> 2-way LDS conflicts (free)

typedef short bf16x8 __attribute__((ext_vector_type(8)));
typedef float f32x4  __attribute__((ext_vector_type(4)));
typedef unsigned long long u64;

union frag { bf16x8 v; u64 d[2]; unsigned int u[4]; unsigned short s[8]; };

__device__ __forceinline__ unsigned short f2bf(float f) {
    union { float f; unsigned int u; } v; v.f = f;
    v.u += 0x7fffu + ((v.u >> 16) & 1u);   // RNE
    return (unsigned short)(v.u >> 16);
}

__device__ __forceinline__ float fast_tanh(float x) {
    float t = __builtin_amdgcn_exp2f(2.885390081777927f * x);
    return 1.0f - 2.0f * __builtin_amdgcn_rcpf(t + 1.0f);
}

__device__ __forceinline__ unsigned int cvt_pk_bf16(float lo, float hi) {
    unsigned int r;
    asm("v_cvt_pk_bf16_f32 %0, %1, %2" : "=v"(r) : "v"(lo), "v"(hi));
    return r;
}

#define MFMA16(A, B, C) __builtin_amdgcn_mfma_f32_16x16x32_bf16((A), (B), (C), 0, 0, 0)

__global__ __launch_bounds__(512, 2) void rnn_persistent(
    const float* __restrict__ x,        // [B][T][N_IN]
    const float* __restrict__ wk,       // [N_IN][N_H]
    const float* __restrict__ wr,       // [N_H][N_H]
    const float* __restrict__ bias,     // [N_H]
    unsigned short* __restrict__ gbuf,  // [2][16][2][8]*128 u64, tt exchange
    unsigned int* __restrict__ flags,   // [16][2] monotonic wave counters
    unsigned short* __restrict__ kbuf,  // [32][8][16][64][8] bf16 kernel frags
    float* __restrict__ lastb)          // [B][N_H] final f32 state
{
    __shared__ unsigned short st[2 * 16 * STRIDE];   // 16.5 KiB, 2 parities
    __shared__ float xlds[2][16 * XPAD];             // 32.5 KiB x-ring

    const int tid  = threadIdx.x;
    const int lane = tid & 63;
    const int w    = tid >> 6;            // wave 0..7
    const int bid  = blockIdx.x;           // 0..31
    const int g    = bid & 15;             // group (pair {g, g+16} co-XCD by %8)
    const int h    = bid >> 4;             // col half 0/1
    const int lm   = lane & 15;
    const int lg   = lane >> 4;
    const int row0 = g * 16;
    const int colbase = h * 256;

    for (int i = tid; i < 2 * 16 * STRIDE; i += 512) st[i] = 0;

    // ---- W_rec B-frags in regs: own-K / partner-K split, const-indexed ----
    bf16x8 WFo[2][8], WFp[2][8];
    #pragma unroll
    for (int n = 0; n < 2; ++n) {
        for (int kc = 0; kc < 8; ++kc) {
            frag fo, fp;
            #pragma unroll
            for (int i = 0; i < 8; ++i) {
                int col = colbase + w * 32 + n * 16 + lm;
                fo.s[i] = f2bf(wr[(size_t)((h * 8 + kc) * 32 + lg * 8 + i) * N_H + col]);
                fp.s[i] = f2bf(wr[(size_t)(((1 - h) * 8 + kc) * 32 + lg * 8 + i) * N_H + col]);
            }
            WFo[n][kc] = fo.v;
            WFp[n][kc] = fp.v;
        }
    }

    // ---- kernel slice -> block-private global kbuf (bf16, frag-ordered) ----
    unsigned short* kb = kbuf + (size_t)bid * (8 * 16 * 64 * 8);
    #pragma unroll
    for (int n = 0; n < 2; ++n) {
        int t = w * 2 + n;
        for (int kc = 0; kc < 8; ++kc) {
            frag f;
            #pragma unroll
            for (int i = 0; i < 8; ++i)
                f.s[i] = f2bf(wk[(size_t)(kc * 32 + lg * 8 + i) * N_H + colbase + t * 16 + lm]);
            *(bf16x8*)&kb[((size_t)(kc * 16 + t) * 64 + lane) * 8] = f.v;
        }
    }
    asm volatile("s_waitcnt vmcnt(0)" ::: "memory");   // kbuf stores complete

    const float bc0 = 0.1f * bias[colbase + w * 32 + lm];
    const float bc1 = 0.1f * bias[colbase + w * 32 + 16 + lm];

    f32x4 prev0 = {0.f, 0.f, 0.f, 0.f};
    f32x4 prev1 = {0.f, 0.f, 0.f, 0.f};

    unsigned int* myflag = &flags[g * 2 + h];
    unsigned int* pflag  = &flags[g * 2 + (1 - h)];

    const float* xrow = x + (size_t)(row0 + lm) * T_SZ * N_IN + lg * 8;

    // ---- prologue: H(0) from direct x loads ----
    f32x4 hc0 = {0.f, 0.f, 0.f, 0.f}, hc1 = {0.f, 0.f, 0.f, 0.f};
    #pragma unroll
    for (int kc = 0; kc < 8; ++kc) {
        f32x4 xa = *(const f32x4*)(xrow + kc * 32);
        f32x4 xb = *(const f32x4*)(xrow + kc * 32 + 4);
        frag a;
        a.u[0] = cvt_pk_bf16(xa[0], xa[1]); a.u[1] = cvt_pk_bf16(xa[2], xa[3]);
        a.u[2] = cvt_pk_bf16(xb[0], xb[1]); a.u[3] = cvt_pk_bf16(xb[2], xb[3]);
        bf16x8 b0 = *(const bf16x8*)&kb[((size_t)(kc * 16 + w * 2    ) * 64 + lane) * 8];
        bf16x8 b1 = *(const bf16x8*)&kb[((size_t)(kc * 16 + w * 2 + 1) * 64 + lane) * 8];
        hc0 = MFMA16(a.v, b0, hc0);
        hc1 = MFMA16(a.v, b1, hc1);
    }

    // ---- prologue: stage x(1) -> xlds[1] ----
    const int xr  = w * 2 + (lane >> 5);     // row this lane stages
    const int xco = (lane & 31) * 8;         // 8 f32 per lane
    {
        const float* xs = x + (size_t)(row0 + xr) * T_SZ * N_IN + (size_t)1 * N_IN + xco;
        *(f32x4*)&xlds[1][xr * XPAD + xco]     = *(const f32x4*)xs;
        *(f32x4*)&xlds[1][xr * XPAD + xco + 4] = *(const f32x4*)(xs + 4);
    }

    // ---- prologue: P(0) loads (gbuf parity 0 is zeroed => tt(0)=0) ----
    frag P[8];
    {
        const u64* pb = (const u64*)gbuf
                      + ((((size_t)0 * 16 + g) * 2 + (1 - h)) * 8) * 128
                      + (lg * 16 + lm) * 2;
        #pragma unroll
        for (int kc = 0; kc < 8; ++kc) {
            P[kc].d[0] = __hip_atomic_load(pb + kc * 128,     __ATOMIC_RELAXED, __HIP_MEMORY_SCOPE_AGENT);
            P[kc].d[1] = __hip_atomic_load(pb + kc * 128 + 1, __ATOMIC_RELAXED, __HIP_MEMORY_SCOPE_AGENT);
        }
    }

    f32x4 hn0, hn1;
    __syncthreads();

    for (int s = 0; s < T_SZ; ++s) {
        const int p = s & 1, q = p ^ 1;

        // ---- C: own-K T-part from LDS ----
        f32x4 a0 = {0.f, 0.f, 0.f, 0.f};
        f32x4 a1 = {0.f, 0.f, 0.f, 0.f};
        const unsigned short* stp = st + p * 16 * STRIDE;
        #pragma unroll
        for (int kc = 0; kc < 8; ++kc) {
            bf16x8 a = *(const bf16x8*)(stp + lm * STRIDE + kc * 32 + lg * 8);
            a0 = MFMA16(a, WFo[0][kc], a0);
            a1 = MFMA16(a, WFo[1][kc], a1);
        }

        // ---- E: partner-K T-part (P loaded last iter / prologue) ----
        #pragma unroll
        for (int kc = 0; kc < 8; ++kc) {
            a0 = MFMA16(P[kc].v, WFp[0][kc], a0);
            a1 = MFMA16(P[kc].v, WFp[1][kc], a1);
        }

        // ---- F: epilogue: leaky update + double tanh -> own cols of st[q] ----
        unsigned short* stq = st + q * 16 * STRIDE;
        #pragma unroll
        for (int n = 0; n < 2; ++n) {
            f32x4 acc = n ? a1 : a0;
            f32x4 hh  = n ? hc1 : hc0;
            float bc  = n ? bc1 : bc0;
            #pragma unroll
            for (int r = 0; r < 4; ++r) {
                float pv = n ? prev1[r] : prev0[r];
                float ns = 0.9f * pv + 0.1f * (acc[r] + hh[r]) + bc;
                float o  = fast_tanh(ns);
                if (n) prev1[r] = o; else prev0[r] = o;
                int row = lg * 4 + r;
                stq[row * STRIDE + (w * 2 + n) * 16 + lm] = f2bf(fast_tanh(o));
                if (s == T_SZ - 1)
                    lastb[(size_t)(row0 + row) * N_H + colbase + (w * 2 + n) * 16 + lm] = o;
            }
        }
        if (s == T_SZ - 1) break;

        // ---- G: publish own slice (frag-ordered), release, count, barrier ----
        {
            frag v;
            v.v = *(const bf16x8*)(stq + lm * STRIDE + w * 32 + lg * 8);
            u64* gp = (u64*)gbuf
                    + ((((size_t)q * 16 + g) * 2 + h) * 8 + w) * 128
                    + (lg * 16 + lm) * 2;
            __hip_atomic_store(gp,     v.d[0], __ATOMIC_RELAXED, __HIP_MEMORY_SCOPE_AGENT);
            __hip_atomic_store(gp + 1, v.d[1], __ATOMIC_RELAXED, __HIP_MEMORY_SCOPE_AGENT);
            asm volatile("s_waitcnt vmcnt(0)" ::: "memory");   // data at IF before flag
            if (lane == 0)
                __hip_atomic_fetch_add(myflag, 1u, __ATOMIC_RELAXED,
                                       __HIP_MEMORY_SCOPE_AGENT);
        }
        __syncthreads();   // st[q] complete for next C; xlds slot consumed

        // ---- X: issue x(s+2) loads to regs (ds_write after poll) ----
        f32x4 xv0, xv1;
        if (s + 2 < T_SZ) {
            const float* xs = x + (size_t)(row0 + xr) * T_SZ * N_IN
                                + (size_t)(s + 2) * N_IN + xco;
            xv0 = *(const f32x4*)xs;
            xv1 = *(const f32x4*)(xs + 4);
        }

        // ---- Hphase: hn = x(s+1)@kernel, in the publish->flag shadow ----
        {
            hn0 = (f32x4){0.f, 0.f, 0.f, 0.f};
            hn1 = (f32x4){0.f, 0.f, 0.f, 0.f};
            const float* xl = &xlds[(s + 1) & 1][0];
            #pragma unroll
            for (int kc = 0; kc < 8; ++kc) {
                f32x4 xa = *(const f32x4*)(xl + lm * XPAD + kc * 32 + lg * 8);
                f32x4 xb = *(const f32x4*)(xl + lm * XPAD + kc * 32 + lg * 8 + 4);
                frag a;
                a.u[0] = cvt_pk_bf16(xa[0], xa[1]); a.u[1] = cvt_pk_bf16(xa[2], xa[3]);
                a.u[2] = cvt_pk_bf16(xb[0], xb[1]); a.u[3] = cvt_pk_bf16(xb[2], xb[3]);
                bf16x8 b0 = *(const bf16x8*)&kb[((size_t)(kc * 16 + w * 2    ) * 64 + lane) * 8];
                bf16x8 b1 = *(const bf16x8*)&kb[((size_t)(kc * 16 + w * 2 + 1) * 64 + lane) * 8];
                hn0 = MFMA16(a.v, b0, hn0);
                hn1 = MFMA16(a.v, b1, hn1);
            }
        }

        // ---- A: poll partner flag ----
        {
            const unsigned int tgt = 8u * (unsigned int)(s + 1);
            while (__hip_atomic_load(pflag, __ATOMIC_RELAXED,
                                     __HIP_MEMORY_SCOPE_AGENT) < tgt)
                __builtin_amdgcn_s_sleep(1);
        }
        __builtin_amdgcn_sched_barrier(0);

        // ---- write x(s+2) into xlds ring ----
        if (s + 2 < T_SZ) {
            *(f32x4*)&xlds[s & 1][xr * XPAD + xco]     = xv0;
            *(f32x4*)&xlds[s & 1][xr * XPAD + xco + 4] = xv1;
        }

        // ---- B: issue P(s+1) loads (consumed at next E) ----
        {
            const u64* pb = (const u64*)gbuf
                          + ((((size_t)q * 16 + g) * 2 + (1 - h)) * 8) * 128
                          + (lg * 16 + lm) * 2;
            #pragma unroll
            for (int kc = 0; kc < 8; ++kc) {
                P[kc].d[0] = __hip_atomic_load(pb + kc * 128,     __ATOMIC_RELAXED, __HIP_MEMORY_SCOPE_AGENT);
                P[kc].d[1] = __hip_atomic_load(pb + kc * 128 + 1, __ATOMIC_RELAXED, __HIP_MEMORY_SCOPE_AGENT);
            }
        }

        hc0 = hn0; hc1 = hn1;
    }
}

__global__ void dense_kernel(const float* __restrict__ last,
                             const float* __restrict__ dw,   // [N_H][N_OUT]
                             const float* __restrict__ db,   // [N_OUT]
                             float* __restrict__ out)        // [B][N_OUT]
{
    const int b = blockIdx.x;
    const int n = threadIdx.x;
    const float* lr = last + (size_t)b * N_H;
    float acc = db[n];
    #pragma unroll 8
    for (int k = 0; k < N_H; ++k)
        acc += lr[k] * dw[(size_t)k * N_OUT + n];
    out[(size_t)b * N_OUT + n] = acc;
}

extern "C" void kernel_launch(void* const* d_in, const int* in_sizes, int n_in,
                              void* d_out, int out_size, void* d_ws, size_t ws_size,
                              hipStream_t stream) {
    const float* x    = (const float*)d_in[0];
    const float* wk   = (const float*)d_in[1];
    const float* wr   = (const float*)d_in[2];
    const float* bias = (const float*)d_in[3];
    const float* dw   = (const float*)d_in[4];
    const float* db   = (const float*)d_in[5];
    float* out = (float*)d_out;

    const size_t GBUF_BYTES = (size_t)2 * 16 * 2 * 8 * 128 * sizeof(u64);   // 512 KiB
    const size_t FLAG_OFF   = GBUF_BYTES;
    const size_t KBUF_OFF   = GBUF_BYTES + 512;                              // flags padded
    const size_t KBUF_BYTES = (size_t)32 * 8 * 16 * 64 * 8 * sizeof(unsigned short); // 4 MiB
    const size_t LAST_OFF   = KBUF_OFF + KBUF_BYTES;

    unsigned short* gbuf  = (unsigned short*)d_ws;
    unsigned int*   flags = (unsigned int*)((char*)d_ws + FLAG_OFF);
    unsigned short* kbuf  = (unsigned short*)((char*)d_ws + KBUF_OFF);
    float*          lastb = (float*)((char*)d_ws + LAST_OFF);

    // zero tt-exchange buffer + flags (tt(0)=0); deterministic per call
    hipMemsetAsync(d_ws, 0, KBUF_OFF, stream);

    void* args[] = { (void*)&x, (void*)&wk, (void*)&wr, (void*)&bias,
                     (void*)&gbuf, (void*)&flags, (void*)&kbuf, (void*)&lastb };
    hipLaunchCooperativeKernel(reinterpret_cast<void*>(rnn_persistent),
                               dim3(32), dim3(512), args, 0, stream);

    dense_kernel<<<dim3(B_SZ), dim3(N_OUT), 0, stream>>>(lastb, dw, db, out);
}

// Round 9
// 7694.418 us; speedup vs baseline: 1.9840x; 1.4759x over previous
//
#include <hip/hip_runtime.h>
#include <hip/hip_bf16.h>

// Leaky-integrator RNN, v5: fully block-local recurrence.
// B=256, T=2048, N_IN=256, N=512, N_OUT=64, ALPHA=0.1
//
// 16 independent blocks (one per 16 batch rows), 8 waves x 64 hidden cols.
// W_rec quantized to int8 (global scale) -> A-frags for ALL 512 cols fit in
// 128 regs/wave -> no cross-block exchange, one __syncthreads per step.
// Swapped-operand MFMA (D' = W^T @ tt^T) puts batch in lane -> tt scatter is
// 4 aligned ds_write_b32. x@kernel computed in 4-step bursts (kernel bf16
// frags streamed from block-private L2-resident kbuf), results packed bf16
// in regs. tt state double-buffered in LDS (i8), x staged 4-steps-ahead in a
// bf16 LDS ring.

#define B_SZ  256
#define T_SZ  2048
#define N_IN  256
#define N_H   512
#define N_OUT 64
#define ST_ROW 528            // bytes per tt row (512 + 16 pad)
#define XROW   272            // u16 per x row (256 + 16 pad)
#define ST_F   166.0f         // tt scale: |tanh(tanh(.))| < 0.7617 -> q < 127

typedef short bf16x8 __attribute__((ext_vector_type(8)));
typedef int   i32x4  __attribute__((ext_vector_type(4)));
typedef float f32x4  __attribute__((ext_vector_type(4)));

__device__ __forceinline__ unsigned short f2bf(float f) {
    union { float f; unsigned int u; } v; v.f = f;
    v.u += 0x7fffu + ((v.u >> 16) & 1u);   // RNE
    return (unsigned short)(v.u >> 16);
}

__device__ __forceinline__ float fast_tanh(float x) {
    float t = __builtin_amdgcn_exp2f(2.885390081777927f * x);
    return 1.0f - 2.0f * __builtin_amdgcn_rcpf(t + 1.0f);
}

__device__ __forceinline__ unsigned int cvt_pk_bf16(float lo, float hi) {
    unsigned int r;
    asm("v_cvt_pk_bf16_f32 %0, %1, %2" : "=v"(r) : "v"(lo), "v"(hi));
    return r;
}

#define MFMA_BF16(A, B, C) __builtin_amdgcn_mfma_f32_16x16x32_bf16((A), (B), (C), 0, 0, 0)
#define MFMA_I8(A, B, C)   __builtin_amdgcn_mfma_i32_16x16x64_i8((A), (B), (C), 0, 0, 0)

__global__ __launch_bounds__(512, 2) void rnn_block(
    const float* __restrict__ x,        // [B][T][N_IN]
    const float* __restrict__ wk,       // [N_IN][N_H]
    const float* __restrict__ wr,       // [N_H][N_H]
    const float* __restrict__ bias,     // [N_H]
    unsigned short* __restrict__ kbuf,  // [16 blocks][256 frags][64 lanes][8] bf16
    float* __restrict__ lastb)          // [B][N_H] final f32 state
{
    __shared__ unsigned char  st[2 * 16 * ST_ROW];     // 16.5 KiB tt-i8, 2 parities
    __shared__ unsigned short xl[2 * 4 * 16 * XROW];   // 68 KiB x-bf16 ring (2 slabs x 4 t)
    __shared__ float biasl[N_H];
    __shared__ float red[512];

    const int tid  = threadIdx.x;
    const int lane = tid & 63;
    const int w    = tid >> 6;          // wave 0..7
    const int lm   = lane & 15;
    const int lg   = lane >> 4;
    const int g    = blockIdx.x;         // 0..15
    const int row0 = g * 16;
    const int c0   = w * 64;             // this wave's first hidden col

    // ---- zero tt state (both parities incl. pad) ----
    for (int i = tid * 4; i < 2 * 16 * ST_ROW; i += 512 * 4)
        *(unsigned int*)&st[i] = 0u;

    // ---- bias -> LDS ----
    if (tid < N_H) biasl[tid] = bias[tid];

    // ---- global |W_rec| max (deterministic per-block reduction) ----
    {
        float m = 0.f;
        for (int k = 0; k < N_H; ++k)
            m = fmaxf(m, fabsf(wr[(size_t)k * N_H + tid]));   // coalesced
        red[tid] = m;
    }
    __syncthreads();
    for (int o = 256; o > 0; o >>= 1) {
        if (tid < o) red[tid] = fmaxf(red[tid], red[tid + o]);
        __syncthreads();
    }
    const float wmax = fmaxf(red[0], 1e-20f);
    const float qs   = 127.0f / wmax;
    const float dq01 = 0.1f * wmax / (127.0f * ST_F);   // 0.1 * dequant factor

    // ---- W_rec^T int8 A-frags: WA[t][kc], lane(lm,lg): A[c=c0+t*16+lm][k=kc*64+lg*16+i] ----
    i32x4 WA[4][8];
    #pragma unroll
    for (int t = 0; t < 4; ++t)
        #pragma unroll
        for (int kc = 0; kc < 8; ++kc) {
            unsigned int d0 = 0, d1 = 0, d2 = 0, d3 = 0;
            #pragma unroll
            for (int i = 0; i < 16; ++i) {
                float wv = wr[(size_t)(kc * 64 + lg * 16 + i) * N_H + c0 + t * 16 + lm];
                int q = (int)rintf(wv * qs);
                unsigned int b = (unsigned int)(q & 0xff) << ((i & 3) * 8);
                if (i < 4) d0 |= b; else if (i < 8) d1 |= b;
                else if (i < 12) d2 |= b; else d3 |= b;
            }
            WA[t][kc] = (i32x4){(int)d0, (int)d1, (int)d2, (int)d3};
        }

    // ---- kernel^T bf16 A-frags -> block-private global kbuf (L2-resident) ----
    unsigned short* kb = kbuf + (size_t)g * (256 * 64 * 8);
    #pragma unroll
    for (int t = 0; t < 4; ++t)
        for (int kc = 0; kc < 8; ++kc) {
            bf16x8 f;
            #pragma unroll
            for (int i = 0; i < 8; ++i)
                f[i] = (short)f2bf(wk[(size_t)(kc * 32 + lg * 8 + i) * N_H + c0 + t * 16 + lm]);
            *(bf16x8*)&kb[(((size_t)((w * 4 + t) * 8 + kc)) * 64 + lane) * 8] = f;
        }

    // ---- stage x for t = 0..3 into slab 0 ----
    const int xrow = tid >> 5;          // 0..15 (batch row)
    const int xco  = (tid & 31) * 8;    // first of 8 f32 cols
    #pragma unroll
    for (int t = 0; t < 4; ++t) {
        const float* xs = x + (size_t)(row0 + xrow) * T_SZ * N_IN + (size_t)t * N_IN + xco;
        f32x4 a = *(const f32x4*)xs, b = *(const f32x4*)(xs + 4);
        i32x4 u = {(int)cvt_pk_bf16(a[0], a[1]), (int)cvt_pk_bf16(a[2], a[3]),
                   (int)cvt_pk_bf16(b[0], b[1]), (int)cvt_pk_bf16(b[2], b[3])};
        *(i32x4*)&xl[((0 * 4 + t) * 16 + xrow) * XROW + xco] = u;
    }
    asm volatile("s_waitcnt vmcnt(0)" ::: "memory");  // kbuf + anything pending
    __syncthreads();

    f32x4 prev[4] = {{0.f,0.f,0.f,0.f},{0.f,0.f,0.f,0.f},{0.f,0.f,0.f,0.f},{0.f,0.f,0.f,0.f}};
    unsigned int hp[4][4][2];           // packed-bf16 h (incl bias): [step j][tile][2]

    for (int s4 = 0; s4 < T_SZ; s4 += 4) {
        const int slab = (s4 >> 2) & 1;

        // ================= H-burst: h(s4..s4+3) = x @ kernel + bias =================
        {
            f32x4 acc[4][4] = {};       // [step j][tile]
            #pragma unroll
            for (int kc = 0; kc < 8; ++kc) {
                bf16x8 kA0 = *(const bf16x8*)&kb[(((size_t)((w * 4 + 0) * 8 + kc)) * 64 + lane) * 8];
                bf16x8 kA1 = *(const bf16x8*)&kb[(((size_t)((w * 4 + 1) * 8 + kc)) * 64 + lane) * 8];
                bf16x8 kA2 = *(const bf16x8*)&kb[(((size_t)((w * 4 + 2) * 8 + kc)) * 64 + lane) * 8];
                bf16x8 kA3 = *(const bf16x8*)&kb[(((size_t)((w * 4 + 3) * 8 + kc)) * 64 + lane) * 8];
                #pragma unroll
                for (int j = 0; j < 4; ++j) {
                    bf16x8 xB = *(const bf16x8*)&xl[((slab * 4 + j) * 16 + lm) * XROW + kc * 32 + lg * 8];
                    acc[j][0] = MFMA_BF16(kA0, xB, acc[j][0]);
                    acc[j][1] = MFMA_BF16(kA1, xB, acc[j][1]);
                    acc[j][2] = MFMA_BF16(kA2, xB, acc[j][2]);
                    acc[j][3] = MFMA_BF16(kA3, xB, acc[j][3]);
                }
            }
            #pragma unroll
            for (int j = 0; j < 4; ++j)
                #pragma unroll
                for (int t = 0; t < 4; ++t) {
                    f32x4 b4 = *(const f32x4*)&biasl[c0 + t * 16 + lg * 4];  // lm-uniform (broadcast)
                    hp[j][t][0] = cvt_pk_bf16(acc[j][t][0] + b4[0], acc[j][t][1] + b4[1]);
                    hp[j][t][1] = cvt_pk_bf16(acc[j][t][2] + b4[2], acc[j][t][3] + b4[3]);
                }
        }

        // ================= 4 recurrence steps =================
        #pragma unroll
        for (int j = 0; j < 4; ++j) {
            const int s = s4 + j;
            const int p = j & 1;
            const bool do_stage = (s + 4 < T_SZ);

            // issue x(s+4) loads early (latency hides under MFMA/epilogue)
            f32x4 xa = {0.f,0.f,0.f,0.f}, xb = {0.f,0.f,0.f,0.f};
            if (do_stage) {
                const float* xs = x + (size_t)(row0 + xrow) * T_SZ * N_IN + (size_t)(s + 4) * N_IN + xco;
                xa = *(const f32x4*)xs;
                xb = *(const f32x4*)(xs + 4);
            }

            // tt B-frags: lane(lm,lg) reads tt_q[batch lm][k = kc*64+lg*16 .. +16]
            i32x4 tb[8];
            #pragma unroll
            for (int kc = 0; kc < 8; ++kc)
                tb[kc] = *(const i32x4*)&st[p * 16 * ST_ROW + lm * ST_ROW + kc * 64 + lg * 16];

            i32x4 ia[4] = {};
            #pragma unroll
            for (int kc = 0; kc < 8; ++kc) {
                ia[0] = MFMA_I8(WA[0][kc], tb[kc], ia[0]);
                ia[1] = MFMA_I8(WA[1][kc], tb[kc], ia[1]);
                ia[2] = MFMA_I8(WA[2][kc], tb[kc], ia[2]);
                ia[3] = MFMA_I8(WA[3][kc], tb[kc], ia[3]);
            }

            // epilogue: lane(lm,lg) holds batch lm, hidden c0+t*16+lg*4+r
            #pragma unroll
            for (int t = 0; t < 4; ++t) {
                union { unsigned int u; float f; } h0, h1, h2, h3;
                h0.u = hp[j][t][0] << 16; h1.u = hp[j][t][0] & 0xffff0000u;
                h2.u = hp[j][t][1] << 16; h3.u = hp[j][t][1] & 0xffff0000u;
                float hh0 = h0.f, hh1 = h1.f, hh2 = h2.f, hh3 = h3.f;
                unsigned int qpack = 0;
                f32x4 o4;
                #pragma unroll
                for (int r = 0; r < 4; ++r) {
                    float hr = (r == 0) ? hh0 : (r == 1) ? hh1 : (r == 2) ? hh2 : hh3;
                    float ns = 0.9f * prev[t][r] + 0.1f * hr + (float)ia[t][r] * dq01;
                    float o  = fast_tanh(ns);
                    prev[t][r] = o;
                    o4[r] = o;
                    float tt = fast_tanh(o);
                    int q = (int)rintf(tt * ST_F);
                    qpack |= (unsigned int)(q & 0xff) << (r * 8);
                }
                *(unsigned int*)&st[(p ^ 1) * 16 * ST_ROW + lm * ST_ROW + c0 + t * 16 + lg * 4] = qpack;
                if (s == T_SZ - 1)
                    *(f32x4*)&lastb[(size_t)(row0 + lm) * N_H + c0 + t * 16 + lg * 4] = o4;
            }

            // write x(s+4) into the other slab
            if (do_stage) {
                i32x4 u = {(int)cvt_pk_bf16(xa[0], xa[1]), (int)cvt_pk_bf16(xa[2], xa[3]),
                           (int)cvt_pk_bf16(xb[0], xb[1]), (int)cvt_pk_bf16(xb[2], xb[3])};
                *(i32x4*)&xl[(((slab ^ 1) * 4 + j) * 16 + xrow) * XROW + xco] = u;
            }

            __syncthreads();   // st[p^1] + xl writes complete
        }
    }
}

__global__ void dense_kernel(const float* __restrict__ last,
                             const float* __restrict__ dw,   // [N_H][N_OUT]
                             const float* __restrict__ db,   // [N_OUT]
                             float* __restrict__ out)        // [B][N_OUT]
{
    const int b = blockIdx.x;
    const int n = threadIdx.x;
    const float* lr = last + (size_t)b * N_H;
    float acc = db[n];
    #pragma unroll 8
    for (int k = 0; k < N_H; ++k)
        acc += lr[k] * dw[(size_t)k * N_OUT + n];
    out[(size_t)b * N_OUT + n] = acc;
}

extern "C" void kernel_launch(void* const* d_in, const int* in_sizes, int n_in,
                              void* d_out, int out_size, void* d_ws, size_t ws_size,
                              hipStream_t stream) {
    const float* x    = (const float*)d_in[0];
    const float* wk   = (const float*)d_in[1];
    const float* wr   = (const float*)d_in[2];
    const float* bias = (const float*)d_in[3];
    const float* dw   = (const float*)d_in[4];
    const float* db   = (const float*)d_in[5];
    float* out = (float*)d_out;

    const size_t KBUF_BYTES = (size_t)16 * 256 * 64 * 8 * sizeof(unsigned short); // 4 MiB
    unsigned short* kbuf  = (unsigned short*)d_ws;
    float*          lastb = (float*)((char*)d_ws + KBUF_BYTES);

    rnn_block<<<dim3(16), dim3(512), 0, stream>>>(x, wk, wr, bias, kbuf, lastb);
    dense_kernel<<<dim3(B_SZ), dim3(N_OUT), 0, stream>>>(lastb, dw, db, out);
}